// Round 1
// baseline (196.374 us; speedup 1.0000x reference)
//
#include <hip/hip_runtime.h>
#include <hip/hip_bf16.h>

#define BB  32
#define SS  1024
#define RR  1024
#define HID 512
#define OUTD 1024

// Kernel 1: one block per batch. Compute o_b = W2*relu(W1*rep_b + b1) + b2
// and write it to out[b, 0, :].
__global__ __launch_bounds__(256) void mlp_head_kernel(
    const float* __restrict__ rep,
    const float* __restrict__ W1, const float* __restrict__ b1,
    const float* __restrict__ W2, const float* __restrict__ b2,
    float* __restrict__ out) {
  __shared__ float s_rep[RR];   // 4 KB
  __shared__ float s_h[HID];    // 2 KB
  const int b   = blockIdx.x;
  const int tid = threadIdx.x;

  // Stage rep_b into LDS (256 threads x float4 = 1024 floats)
  const float4* rep4 = reinterpret_cast<const float4*>(rep + (size_t)b * RR);
  reinterpret_cast<float4*>(s_rep)[tid] = rep4[tid];
  __syncthreads();

  const int wave = tid >> 6;
  const int lane = tid & 63;
  const int g    = lane >> 4;   // 4 row-groups per wave
  const int l16  = lane & 15;   // 16 lanes cooperate on one row

  // ---- Layer 1: h[j] = relu(W1[j,:]·rep + b1[j]), 512 rows, 128 per wave ----
  for (int rbase = wave * 128; rbase < wave * 128 + 128; rbase += 4) {
    const int row = rbase + g;
    const float4* w = reinterpret_cast<const float4*>(W1 + (size_t)row * RR);
    float acc = 0.f;
#pragma unroll
    for (int t = 0; t < 16; ++t) {           // 1024 elems / 16 lanes = 16 float4
      const float4 wv = w[l16 + 16 * t];
      const float4 rv = reinterpret_cast<const float4*>(s_rep)[l16 + 16 * t];
      acc += wv.x * rv.x + wv.y * rv.y + wv.z * rv.z + wv.w * rv.w;
    }
    acc += __shfl_xor(acc, 1);
    acc += __shfl_xor(acc, 2);
    acc += __shfl_xor(acc, 4);
    acc += __shfl_xor(acc, 8);
    if (l16 == 0) s_h[row] = fmaxf(acc + b1[row], 0.f);
  }
  __syncthreads();

  // ---- Layer 2: o[k] = W2[k,:]·h + b2[k], 1024 rows, 256 per wave ----
  float* outb = out + (size_t)b * SS * OUTD;  // s = 0 row
  for (int rbase = wave * 256; rbase < wave * 256 + 256; rbase += 4) {
    const int row = rbase + g;
    const float4* w = reinterpret_cast<const float4*>(W2 + (size_t)row * HID);
    float acc = 0.f;
#pragma unroll
    for (int t = 0; t < 8; ++t) {            // 512 elems / 16 lanes = 8 float4
      const float4 wv = w[l16 + 16 * t];
      const float4 hv = reinterpret_cast<const float4*>(s_h)[l16 + 16 * t];
      acc += wv.x * hv.x + wv.y * hv.y + wv.z * hv.z + wv.w * hv.w;
    }
    acc += __shfl_xor(acc, 1);
    acc += __shfl_xor(acc, 2);
    acc += __shfl_xor(acc, 4);
    acc += __shfl_xor(acc, 8);
    if (l16 == 0) outb[row] = acc + b2[row];
  }
}

// Kernel 2: broadcast out[b,0,:] to out[b,s,:] for s >= 1 (float4 grid-stride).
__global__ __launch_bounds__(256) void bcast_kernel(float* __restrict__ out) {
  const int N4 = BB * SS * OUTD / 4;          // 8,388,608 float4s
  const int stride = gridDim.x * blockDim.x;
  float4* __restrict__ o4p = reinterpret_cast<float4*>(out);
  for (int i = blockIdx.x * blockDim.x + threadIdx.x; i < N4; i += stride) {
    const int b  = i >> 18;                   // S*OUT/4 = 2^18 per batch
    const int o4 = i & (OUTD / 4 - 1);        // 0..255
    const int s  = (i >> 8) & (SS - 1);       // 0..1023
    const float4 v = o4p[((size_t)b << 18) + o4];  // source: s=0 row (L2-hot)
    if (s != 0) o4p[i] = v;
  }
}

extern "C" void kernel_launch(void* const* d_in, const int* in_sizes, int n_in,
                              void* d_out, int out_size, void* d_ws, size_t ws_size,
                              hipStream_t stream) {
  const float* rep = (const float*)d_in[0];
  // d_in[1] = size_matrix: only its shape matters (ones_like) -> unused
  const float* W1 = (const float*)d_in[2];
  const float* b1 = (const float*)d_in[3];
  const float* W2 = (const float*)d_in[4];
  const float* b2 = (const float*)d_in[5];
  float* out = (float*)d_out;

  mlp_head_kernel<<<BB, 256, 0, stream>>>(rep, W1, b1, W2, b2, out);
  bcast_kernel<<<2048, 256, 0, stream>>>(out);
}

// Round 2
// 39.513 us; speedup vs baseline: 4.9699x; 4.9699x over previous
//
#include <hip/hip_runtime.h>
#include <hip/hip_bf16.h>

#define BB  32
#define SS  1024
#define RR  1024
#define HID 512
#define OUTD 1024

// Layer 1: one wave per (b, j). h[b*HID+j] = relu(W1[j,:]·rep[b,:] + b1[j])
__global__ __launch_bounds__(256) void layer1_kernel(
    const float* __restrict__ rep, const float* __restrict__ W1,
    const float* __restrict__ b1, float* __restrict__ h) {
  const int gwave = (blockIdx.x * 256 + threadIdx.x) >> 6;  // 0 .. 32*512-1
  const int lane  = threadIdx.x & 63;
  const int b = gwave >> 9;          // /HID
  const int j = gwave & (HID - 1);

  const float4* w = reinterpret_cast<const float4*>(W1 + (size_t)j * RR);
  const float4* r = reinterpret_cast<const float4*>(rep + (size_t)b * RR);
  float acc = 0.f;
#pragma unroll
  for (int t = 0; t < 4; ++t) {      // 1024 floats = 256 float4 / 64 lanes
    const float4 wv = w[lane + 64 * t];
    const float4 rv = r[lane + 64 * t];
    acc += wv.x * rv.x + wv.y * rv.y + wv.z * rv.z + wv.w * rv.w;
  }
  acc += __shfl_xor(acc, 1);
  acc += __shfl_xor(acc, 2);
  acc += __shfl_xor(acc, 4);
  acc += __shfl_xor(acc, 8);
  acc += __shfl_xor(acc, 16);
  acc += __shfl_xor(acc, 32);
  if (lane == 0) h[gwave] = fmaxf(acc + b1[j], 0.f);
}

// Layer 2: one wave per (b, k). out[b, 0, k] = W2[k,:]·h[b,:] + b2[k]
__global__ __launch_bounds__(256) void layer2_kernel(
    const float* __restrict__ h, const float* __restrict__ W2,
    const float* __restrict__ b2, float* __restrict__ out) {
  const int gwave = (blockIdx.x * 256 + threadIdx.x) >> 6;  // 0 .. 32*1024-1
  const int lane  = threadIdx.x & 63;
  const int b = gwave >> 10;         // /OUTD
  const int k = gwave & (OUTD - 1);

  const float4* w  = reinterpret_cast<const float4*>(W2 + (size_t)k * HID);
  const float4* hv = reinterpret_cast<const float4*>(h + (size_t)b * HID);
  float acc = 0.f;
#pragma unroll
  for (int t = 0; t < 2; ++t) {      // 512 floats = 128 float4 / 64 lanes
    const float4 wv = w[lane + 64 * t];
    const float4 xv = hv[lane + 64 * t];
    acc += wv.x * xv.x + wv.y * xv.y + wv.z * xv.z + wv.w * xv.w;
  }
  acc += __shfl_xor(acc, 1);
  acc += __shfl_xor(acc, 2);
  acc += __shfl_xor(acc, 4);
  acc += __shfl_xor(acc, 8);
  acc += __shfl_xor(acc, 16);
  acc += __shfl_xor(acc, 32);
  if (lane == 0) out[(size_t)b * SS * OUTD + k] = acc + b2[k];
}

// Broadcast: block register-caches out[b,0,:] (1 float4/thread) and streams
// it to 16 s-rows. Grid = 32 batches x 64 chunks.
__global__ __launch_bounds__(256) void bcast_kernel(float* __restrict__ out) {
  const int b     = blockIdx.x >> 6;
  const int chunk = blockIdx.x & 63;
  float4* __restrict__ base = reinterpret_cast<float4*>(out + (size_t)b * SS * OUTD);
  const float4 v = base[threadIdx.x];          // source row s=0 (256 float4)
  const int s0 = chunk * 16;
#pragma unroll
  for (int i = 0; i < 16; ++i) {
    const int s = s0 + i;
    if (s != 0) base[(size_t)s * (OUTD / 4) + threadIdx.x] = v;
  }
}

extern "C" void kernel_launch(void* const* d_in, const int* in_sizes, int n_in,
                              void* d_out, int out_size, void* d_ws, size_t ws_size,
                              hipStream_t stream) {
  const float* rep = (const float*)d_in[0];
  // d_in[1] = size_matrix: only its shape matters (ones_like) -> unused
  const float* W1 = (const float*)d_in[2];
  const float* b1 = (const float*)d_in[3];
  const float* W2 = (const float*)d_in[4];
  const float* b2 = (const float*)d_in[5];
  float* out = (float*)d_out;
  float* h   = (float*)d_ws;                   // 32*512 floats = 64 KB

  layer1_kernel<<<BB * HID / 4, 256, 0, stream>>>(rep, W1, b1, h);
  layer2_kernel<<<BB * OUTD / 4, 256, 0, stream>>>(h, W2, b2, out);
  bcast_kernel<<<BB * 64, 256, 0, stream>>>(out);
}